// Round 1
// baseline (7335.175 us; speedup 1.0000x reference)
//
#include <hip/hip_runtime.h>
#include <hip/hip_fp16.h>
#include <stdint.h>

#define TT 1024
#define BB 64
#define DHH 256
#define HH 512
#define G3 1536

typedef _Float16 f16;
typedef _Float16 f16x4 __attribute__((ext_vector_type(4)));
typedef _Float16 f16x8 __attribute__((ext_vector_type(8)));
typedef float f32x4 __attribute__((ext_vector_type(4)));
typedef unsigned long long u64;

__device__ __forceinline__ float sigm(float x){ return 1.0f/(1.0f+__expf(-x)); }
__device__ __forceinline__ float tanh_f(float x){ return 2.0f/(1.0f+__expf(-2.0f*x)) - 1.0f; }

// ---------------- prep: f32->f16 weights, folded bias ----------------
__global__ void k_prep(const float* __restrict__ wih, const float* __restrict__ whh,
                       const float* __restrict__ bih, const float* __restrict__ bhh,
                       f16* __restrict__ wih_h, f16* __restrict__ whh_h, float* __restrict__ biasf){
  int i = blockIdx.x*256 + threadIdx.x;
  if (i < G3*HH){ wih_h[i] = (f16)wih[i]; whh_h[i] = (f16)whh[i]; }
  // fold b_ih (all gates) + b_hh (r,z gates only; n-gate's b_hh stays inside r*(...))
  if (i < G3) biasf[i] = bih[i] + (i < 2*HH ? bhh[i] : 0.0f);
}

// ---------------- build x = concat(s, p.sum(axis=2)) as f16 [T*B][512] ----------------
__global__ void k_buildx(const float* __restrict__ s, const float* __restrict__ p, f16* __restrict__ x){
  int m = blockIdx.x;             // m = t*64 + b
  int t = m >> 6, b = m & 63;
  int l = threadIdx.x;            // 0..63 -> 4 floats each
  const float4* s4 = reinterpret_cast<const float4*>(s + ((size_t)b*TT + t)*DHH);
  const float4* p4 = reinterpret_cast<const float4*>(p + ((size_t)b*TT + t)*8*DHH);
  float4 sv = s4[l];
  float4 a  = p4[l];
#pragma unroll
  for (int k=1;k<8;k++){ float4 v = p4[k*64 + l]; a.x+=v.x; a.y+=v.y; a.z+=v.z; a.w+=v.w; }
  f16* xr = x + (size_t)m*HH;
  f16x4 hs = { (f16)sv.x,(f16)sv.y,(f16)sv.z,(f16)sv.w };
  f16x4 hp = { (f16)a.x,(f16)a.y,(f16)a.z,(f16)a.w };
  *reinterpret_cast<f16x4*>(xr + l*4)       = hs;
  *reinterpret_cast<f16x4*>(xr + 256 + l*4) = hp;
}

// ---------------- gi GEMM: D[wrow][xrow] = sum_k W_ih[wrow][k] * x[xrow][k]  (+bias) ----------------
// Writes gi in scan-friendly layout: gi[((t*16+ksl)*4+g)*16 + b'][96] f16, 96 = gate*32 + j'
#define LDAP 72
__global__ __launch_bounds__(256) void k_gemm(const f16* __restrict__ x, const f16* __restrict__ w,
                       const float* __restrict__ biasf, f16* __restrict__ gi){
  __shared__ f16 lA[128*LDAP];   // W tile   [128 wrows][64 k] padded
  __shared__ f16 lB[128*LDAP];   // x tile   [128 xrows][64 k] padded
  int by = blockIdx.x;           // wrow tile (12)
  int bx = blockIdx.y;           // xrow tile (512)
  int tid = threadIdx.x, l = tid & 63, wv = tid >> 6;
  int wm = wv >> 1, wn = wv & 1;

  f32x4 acc[4][4];
#pragma unroll
  for (int i=0;i<4;i++)
#pragma unroll
    for (int j=0;j<4;j++) acc[i][j] = (f32x4){0.f,0.f,0.f,0.f};

  for (int kt = 0; kt < 8; ++kt){
#pragma unroll
    for (int r = 0; r < 4; ++r){
      int c = tid + 256*r;            // 1024 chunks of 16B
      int row = c >> 3, o = c & 7;
      f16x8 va = *reinterpret_cast<const f16x8*>(w + (size_t)(by*128+row)*HH + kt*64 + o*8);
      f16x8 vb = *reinterpret_cast<const f16x8*>(x + (size_t)(bx*128+row)*HH + kt*64 + o*8);
      *reinterpret_cast<f16x8*>(&lA[row*LDAP + o*8]) = va;
      *reinterpret_cast<f16x8*>(&lB[row*LDAP + o*8]) = vb;
    }
    __syncthreads();
#pragma unroll
    for (int kk = 0; kk < 2; ++kk){
      f16x8 aF[4], bF[4];
#pragma unroll
      for (int mi=0;mi<4;mi++)
        aF[mi] = *reinterpret_cast<const f16x8*>(&lA[(wm*64+mi*16+(l&15))*LDAP + kk*32 + (l>>4)*8]);
#pragma unroll
      for (int ni=0;ni<4;ni++)
        bF[ni] = *reinterpret_cast<const f16x8*>(&lB[(wn*64+ni*16+(l&15))*LDAP + kk*32 + (l>>4)*8]);
#pragma unroll
      for (int mi=0;mi<4;mi++)
#pragma unroll
        for (int ni=0;ni<4;ni++)
          acc[mi][ni] = __builtin_amdgcn_mfma_f32_16x16x32_f16(aF[mi], bF[ni], acc[mi][ni], 0,0,0);
    }
    __syncthreads();
  }
  // epilogue: D m = (l>>4)*4+reg -> 4 consecutive wrows; n = l&15 -> xrow
#pragma unroll
  for (int mi=0;mi<4;mi++){
    int wrow0 = by*128 + wm*64 + mi*16 + (l>>4)*4;
    float4 bv = *reinterpret_cast<const float4*>(biasf + wrow0);
    int gate = wrow0 >> 9, j = wrow0 & 511, ksl = j >> 5, rp = gate*32 + (j&31);
#pragma unroll
    for (int ni=0;ni<4;ni++){
      int xrow = bx*128 + wn*64 + ni*16 + (l&15);
      int t = xrow >> 6, g = (xrow>>4)&3, bp = xrow & 15;
      size_t dst = ((((size_t)t*16 + ksl)*4 + g)*16 + bp)*96 + rp;
      union { u64 u; f16x4 h; } cv;
      cv.h = (f16x4){ (f16)(acc[mi][ni][0]+bv.x), (f16)(acc[mi][ni][1]+bv.y),
                      (f16)(acc[mi][ni][2]+bv.z), (f16)(acc[mi][ni][3]+bv.w) };
      *reinterpret_cast<u64*>(gi + dst) = cv.u;
    }
  }
}

// ---------------- persistent GRU scan ----------------
// 64 WGs = 4 batch-groups (16 batches) x 16 j-slices (32 j each -> 96 W rows in LDS).
// Per step: MFMA gh = W_slice @ h^T, lane-local gates, u64 agent-atomic h exchange + flags.
#define WLD 536
__global__ __launch_bounds__(128, 1) void k_scan(const f16* __restrict__ whh_h, const f16* __restrict__ gi,
                      const float* __restrict__ bhh, f16* __restrict__ hh,
                      unsigned* __restrict__ flags){
  extern __shared__ char smem[];
  f16* Wl = reinterpret_cast<f16*>(smem);               // [96][WLD]
  f16* hb = reinterpret_cast<f16*>(smem + 96*WLD*2);    // [16][WLD]
  const int g = blockIdx.x & 3, ksl = blockIdx.x >> 2;
  const int tid = threadIdx.x, l = tid & 63, wv = tid >> 6;

  // load W slice rows: local row = gate*32 + j', global row = gate*512 + ksl*32 + j'
  for (int rr = 0; rr < 48; ++rr){
    int row = wv*48 + rr;
    int grow = (row>>5)*512 + ksl*32 + (row&31);
    f16x8 v = *reinterpret_cast<const f16x8*>(whh_h + (size_t)grow*HH + l*8);
    *reinterpret_cast<f16x8*>(&Wl[row*WLD + l*8]) = v;
  }
  const int jl = wv*16 + (l>>4)*4;       // 4 consecutive j-locals (via regs)
  const int jglob = ksl*32 + jl;
  float4 bnv = *reinterpret_cast<const float4*>(bhh + 2*HH + jglob);   // b_hh n-gate
  float bna[4] = {bnv.x, bnv.y, bnv.z, bnv.w};
  const int bp = l & 15;                 // batch within group (MFMA N/col)
  const int bglob = g*16 + bp;
  __syncthreads();

  for (int t = 0; t < TT; ++t){
    // ---- 1. h_{t-1} -> hb ----
    if (t == 0){
      for (int i = tid; i < 16*WLD*2/8; i += 128) reinterpret_cast<u64*>(hb)[i] = 0ull;
    } else {
      if (l < 16){
        const unsigned fidx = ((unsigned)(t-1)*4 + g)*16 + l;
        while (__hip_atomic_load(&flags[fidx], __ATOMIC_ACQUIRE, __HIP_MEMORY_SCOPE_AGENT) == 0u)
          __builtin_amdgcn_s_sleep(1);
      }
      __syncthreads();   // all 16 slice-flags confirmed by both waves
      int b = tid >> 3, ch = tid & 7;
      const u64* src = reinterpret_cast<const u64*>(hh + ((size_t)(t-1)*64 + g*16 + b)*HH + ch*64);
      u64* dstp = reinterpret_cast<u64*>(&hb[b*WLD + ch*64]);
#pragma unroll
      for (int q = 0; q < 16; ++q)
        dstp[q] = __hip_atomic_load(src + q, __ATOMIC_RELAXED, __HIP_MEMORY_SCOPE_AGENT);
    }
    __syncthreads();

    // ---- 2. gi / h_old fetch ----
    const f16* gib = gi + ((((size_t)t*16 + ksl)*4 + g)*16 + bp)*96;
    union { u64 u; f16x4 h; } cr, cz, cn, ho, hn;
    cr.u = *reinterpret_cast<const u64*>(gib + jl);
    cz.u = *reinterpret_cast<const u64*>(gib + 32 + jl);
    cn.u = *reinterpret_cast<const u64*>(gib + 64 + jl);
    ho.u = *reinterpret_cast<const u64*>(&hb[bp*WLD + jglob]);

    // ---- 3. gh = W_slice @ h : A=W rows (m), B=h (n=batch) ----
    f32x4 aR = (f32x4){0.f,0.f,0.f,0.f};
    f32x4 aZ = (f32x4){0.f,0.f,0.f,0.f};
    f32x4 aN = (f32x4){0.f,0.f,0.f,0.f};
#pragma unroll
    for (int kt = 0; kt < 16; ++kt){
      f16x8 bF = *reinterpret_cast<const f16x8*>(&hb[(l&15)*WLD + kt*32 + (l>>4)*8]);
      f16x8 a0 = *reinterpret_cast<const f16x8*>(&Wl[(     wv*16 + (l&15))*WLD + kt*32 + (l>>4)*8]);
      f16x8 a1 = *reinterpret_cast<const f16x8*>(&Wl[(32 + wv*16 + (l&15))*WLD + kt*32 + (l>>4)*8]);
      f16x8 a2 = *reinterpret_cast<const f16x8*>(&Wl[(64 + wv*16 + (l&15))*WLD + kt*32 + (l>>4)*8]);
      aR = __builtin_amdgcn_mfma_f32_16x16x32_f16(a0, bF, aR, 0,0,0);
      aZ = __builtin_amdgcn_mfma_f32_16x16x32_f16(a1, bF, aZ, 0,0,0);
      aN = __builtin_amdgcn_mfma_f32_16x16x32_f16(a2, bF, aN, 0,0,0);
    }

    // ---- 4. gates (lane-local: 4 consecutive j, one batch) ----
#pragma unroll
    for (int r=0;r<4;r++){
      float rg = sigm((float)cr.h[r] + aR[r]);
      float zg = sigm((float)cz.h[r] + aZ[r]);
      float ng = tanh_f((float)cn.h[r] + rg*(aN[r] + bna[r]));
      float hv = (1.0f - zg)*ng + zg*(float)ho.h[r];
      hn.h[r] = (f16)hv;
    }
    u64* hdst = reinterpret_cast<u64*>(hh + ((size_t)t*64 + bglob)*HH + jglob);
    __hip_atomic_store(hdst, hn.u, __ATOMIC_RELAXED, __HIP_MEMORY_SCOPE_AGENT);

    __syncthreads();   // drains all waves' stores (waitcnt before barrier)
    if (tid == 0)
      __hip_atomic_store(&flags[((unsigned)t*4 + g)*16 + ksl], 1u, __ATOMIC_RELEASE, __HIP_MEMORY_SCOPE_AGENT);
  }
}

// ---------------- rewards = sigmoid(h @ W_t + b_t) ----------------
__global__ void k_reward(const f16* __restrict__ hh, const float* __restrict__ wt,
                         const float* __restrict__ bt, float* __restrict__ out){
  int wv = threadIdx.x >> 6, l = threadIdx.x & 63;
  int idx = blockIdx.x*4 + wv;          // idx = b*1024 + t (output order [B][T])
  int b = idx >> 10, t = idx & 1023;
  const f16* hr = hh + ((size_t)t*64 + b)*HH;
  f16x8 hv = *reinterpret_cast<const f16x8*>(hr + l*8);
  float4 w0 = *reinterpret_cast<const float4*>(wt + l*8);
  float4 w1 = *reinterpret_cast<const float4*>(wt + l*8 + 4);
  float sum = (float)hv[0]*w0.x + (float)hv[1]*w0.y + (float)hv[2]*w0.z + (float)hv[3]*w0.w
            + (float)hv[4]*w1.x + (float)hv[5]*w1.y + (float)hv[6]*w1.z + (float)hv[7]*w1.w;
#pragma unroll
  for (int m=32;m>=1;m>>=1) sum += __shfl_xor(sum, m);
  if (l==0) out[idx] = sigm(sum + bt[0]);
}

extern "C" void kernel_launch(void* const* d_in, const int* in_sizes, int n_in,
                              void* d_out, int out_size, void* d_ws, size_t ws_size,
                              hipStream_t stream) {
  const float* s   = (const float*)d_in[0];
  const float* p   = (const float*)d_in[1];
  const float* wih = (const float*)d_in[2];
  const float* whh = (const float*)d_in[3];
  const float* bih = (const float*)d_in[4];
  const float* bhh = (const float*)d_in[5];
  const float* wt  = (const float*)d_in[6];
  const float* bt  = (const float*)d_in[7];
  float* out = (float*)d_out;

  char* ws = (char*)d_ws;
  size_t o = 0;
  auto take = [&](size_t bytes)->char*{ char* r = ws + o; o = (o + bytes + 255) & ~(size_t)255; return r; };
  f16*      x_h   = (f16*)   take((size_t)TT*BB*HH*2);       // 67 MB
  f16*      wih_h = (f16*)   take((size_t)G3*HH*2);
  f16*      whh_h = (f16*)   take((size_t)G3*HH*2);
  float*    biasf = (float*) take((size_t)G3*4);
  f16*      gi_s  = (f16*)   take((size_t)TT*BB*G3*2);       // 201 MB
  f16*      hh    = (f16*)   take((size_t)TT*BB*HH*2);       // 67 MB
  unsigned* flags = (unsigned*)take((size_t)TT*64*4);        // 256 KB
  (void)ws_size; (void)in_sizes; (void)n_in; (void)out_size;

  hipMemsetAsync(flags, 0, (size_t)TT*64*4, stream);
  k_prep  <<<3072, 256, 0, stream>>>(wih, whh, bih, bhh, wih_h, whh_h, biasf);
  k_buildx<<<TT*BB, 64, 0, stream>>>(s, p, x_h);
  k_gemm  <<<dim3(12, 512), 256, 0, stream>>>(x_h, wih_h, biasf, gi_s);
  hipFuncSetAttribute((const void*)k_scan, hipFuncAttributeMaxDynamicSharedMemorySize, (96+16)*WLD*2);
  k_scan  <<<64, 128, (96+16)*WLD*2, stream>>>(whh_h, gi_s, bhh, hh, flags);
  k_reward<<<TT*BB/4, 256, 0, stream>>>(hh, wt, bt, out);
}

// Round 2
// 5076.910 us; speedup vs baseline: 1.4448x; 1.4448x over previous
//
#include <hip/hip_runtime.h>
#include <hip/hip_fp16.h>
#include <stdint.h>

#define TT 1024
#define BB 64
#define DHH 256
#define HH 512
#define G3 1536

typedef _Float16 f16;
typedef _Float16 f16x4 __attribute__((ext_vector_type(4)));
typedef _Float16 f16x8 __attribute__((ext_vector_type(8)));
typedef float f32x4 __attribute__((ext_vector_type(4)));
typedef unsigned long long u64;

__device__ __forceinline__ float sigm(float x){ return 1.0f/(1.0f+__expf(-x)); }
__device__ __forceinline__ float tanh_f(float x){ return 2.0f/(1.0f+__expf(-2.0f*x)) - 1.0f; }

// ---------------- prep: f32->f16 weights, folded bias ----------------
__global__ void k_prep(const float* __restrict__ wih, const float* __restrict__ whh,
                       const float* __restrict__ bih, const float* __restrict__ bhh,
                       f16* __restrict__ wih_h, f16* __restrict__ whh_h, float* __restrict__ biasf){
  int i = blockIdx.x*256 + threadIdx.x;
  if (i < G3*HH){ wih_h[i] = (f16)wih[i]; whh_h[i] = (f16)whh[i]; }
  // fold b_ih (all gates) + b_hh (r,z gates only; n-gate's b_hh stays inside r*(...))
  if (i < G3) biasf[i] = bih[i] + (i < 2*HH ? bhh[i] : 0.0f);
}

// ---------------- build x = concat(s, p.sum(axis=2)) as f16 [T*B][512] ----------------
__global__ void k_buildx(const float* __restrict__ s, const float* __restrict__ p, f16* __restrict__ x){
  int m = blockIdx.x;             // m = t*64 + b
  int t = m >> 6, b = m & 63;
  int l = threadIdx.x;            // 0..63 -> 4 floats each
  const float4* s4 = reinterpret_cast<const float4*>(s + ((size_t)b*TT + t)*DHH);
  const float4* p4 = reinterpret_cast<const float4*>(p + ((size_t)b*TT + t)*8*DHH);
  float4 sv = s4[l];
  float4 a  = p4[l];
#pragma unroll
  for (int k=1;k<8;k++){ float4 v = p4[k*64 + l]; a.x+=v.x; a.y+=v.y; a.z+=v.z; a.w+=v.w; }
  f16* xr = x + (size_t)m*HH;
  f16x4 hs = { (f16)sv.x,(f16)sv.y,(f16)sv.z,(f16)sv.w };
  f16x4 hp = { (f16)a.x,(f16)a.y,(f16)a.z,(f16)a.w };
  *reinterpret_cast<f16x4*>(xr + l*4)       = hs;
  *reinterpret_cast<f16x4*>(xr + 256 + l*4) = hp;
}

// ---------------- gi GEMM: D[wrow][xrow] = sum_k W_ih[wrow][k] * x[xrow][k]  (+bias) ----------------
// Writes gi in scan-friendly layout: gi[((t*16+ksl)*4+g)*16 + b'][96] f16, 96 = gate*32 + j'
#define LDAP 72
__global__ __launch_bounds__(256) void k_gemm(const f16* __restrict__ x, const f16* __restrict__ w,
                       const float* __restrict__ biasf, f16* __restrict__ gi){
  __shared__ f16 lA[128*LDAP];   // W tile   [128 wrows][64 k] padded
  __shared__ f16 lB[128*LDAP];   // x tile   [128 xrows][64 k] padded
  int by = blockIdx.x;           // wrow tile (12)
  int bx = blockIdx.y;           // xrow tile (512)
  int tid = threadIdx.x, l = tid & 63, wv = tid >> 6;
  int wm = wv >> 1, wn = wv & 1;

  f32x4 acc[4][4];
#pragma unroll
  for (int i=0;i<4;i++)
#pragma unroll
    for (int j=0;j<4;j++) acc[i][j] = (f32x4){0.f,0.f,0.f,0.f};

  for (int kt = 0; kt < 8; ++kt){
#pragma unroll
    for (int r = 0; r < 4; ++r){
      int c = tid + 256*r;            // 1024 chunks of 16B
      int row = c >> 3, o = c & 7;
      f16x8 va = *reinterpret_cast<const f16x8*>(w + (size_t)(by*128+row)*HH + kt*64 + o*8);
      f16x8 vb = *reinterpret_cast<const f16x8*>(x + (size_t)(bx*128+row)*HH + kt*64 + o*8);
      *reinterpret_cast<f16x8*>(&lA[row*LDAP + o*8]) = va;
      *reinterpret_cast<f16x8*>(&lB[row*LDAP + o*8]) = vb;
    }
    __syncthreads();
#pragma unroll
    for (int kk = 0; kk < 2; ++kk){
      f16x8 aF[4], bF[4];
#pragma unroll
      for (int mi=0;mi<4;mi++)
        aF[mi] = *reinterpret_cast<const f16x8*>(&lA[(wm*64+mi*16+(l&15))*LDAP + kk*32 + (l>>4)*8]);
#pragma unroll
      for (int ni=0;ni<4;ni++)
        bF[ni] = *reinterpret_cast<const f16x8*>(&lB[(wn*64+ni*16+(l&15))*LDAP + kk*32 + (l>>4)*8]);
#pragma unroll
      for (int mi=0;mi<4;mi++)
#pragma unroll
        for (int ni=0;ni<4;ni++)
          acc[mi][ni] = __builtin_amdgcn_mfma_f32_16x16x32_f16(aF[mi], bF[ni], acc[mi][ni], 0,0,0);
    }
    __syncthreads();
  }
  // epilogue: D m = (l>>4)*4+reg -> 4 consecutive wrows; n = l&15 -> xrow
#pragma unroll
  for (int mi=0;mi<4;mi++){
    int wrow0 = by*128 + wm*64 + mi*16 + (l>>4)*4;
    float4 bv = *reinterpret_cast<const float4*>(biasf + wrow0);
    int gate = wrow0 >> 9, j = wrow0 & 511, ksl = j >> 5, rp = gate*32 + (j&31);
#pragma unroll
    for (int ni=0;ni<4;ni++){
      int xrow = bx*128 + wn*64 + ni*16 + (l&15);
      int t = xrow >> 6, g = (xrow>>4)&3, bp = xrow & 15;
      size_t dst = ((((size_t)t*16 + ksl)*4 + g)*16 + bp)*96 + rp;
      union { u64 u; f16x4 h; } cv;
      cv.h = (f16x4){ (f16)(acc[mi][ni][0]+bv.x), (f16)(acc[mi][ni][1]+bv.y),
                      (f16)(acc[mi][ni][2]+bv.z), (f16)(acc[mi][ni][3]+bv.w) };
      *reinterpret_cast<u64*>(gi + dst) = cv.u;
    }
  }
}

// ---------------- persistent GRU scan (fence-free, LDS-free, barrier-free) ----------------
// 128 single-wave WGs = 4 batch-groups (16 batches) x 16 j-slices (32 j) x 2 wave-halves (16 j each).
// W_hh slice lives in 192 VGPRs. Cross-WG h exchange: relaxed agent atomics (MALL-serialized),
// producer orders data-ack before per-wave flag via inline s_waitcnt vmcnt(0).
__global__ __launch_bounds__(64) void k_scan(const f16* __restrict__ whh_h, const f16* __restrict__ gi,
                      const float* __restrict__ bhh, f16* __restrict__ hh,
                      unsigned* __restrict__ flags){
  const int bid = blockIdx.x;                       // 0..127
  const int g = bid & 3, ksl = (bid >> 2) & 15, wv = bid >> 6;
  const int l = threadIdx.x;                        // 0..63
  const int lm = l & 15, lh = l >> 4;

  // persistent A-fragments: aW[gate][kt], W row = gate*512 + ksl*32 + wv*16 + lm, k = kt*32 + lh*8
  f16x8 aW[3][16];
#pragma unroll
  for (int gate = 0; gate < 3; ++gate){
    const f16* wr = whh_h + ((size_t)gate*512 + ksl*32 + wv*16 + lm)*HH + lh*8;
#pragma unroll
    for (int kt = 0; kt < 16; ++kt)
      aW[gate][kt] = *reinterpret_cast<const f16x8*>(wr + kt*32);
  }
  const int jl    = wv*16 + lh*4;                   // first of 4 j-locals this lane owns
  const int jglob = ksl*32 + jl;
  float4 bnv = *reinterpret_cast<const float4*>(bhh + 2*HH + jglob);   // b_hh n-gate
  float bna[4] = {bnv.x, bnv.y, bnv.z, bnv.w};
  const int bp = lm, bglob = g*16 + bp;

  union U64H { u64 u; f16x4 h; };
  U64H ho; ho.u = 0ull;                             // h_{t-1} for this lane's (4j, b) = own prev output

  for (int t = 0; t < TT; ++t){
    // ---- gi prefetch (independent of h_{t-1}); pin issue before the poll ----
    const f16* gib = gi + ((((size_t)t*16 + ksl)*4 + g)*16 + bp)*96;
    U64H cr, cz, cn, hn;
    cr.u = *reinterpret_cast<const u64*>(gib + jl);
    cz.u = *reinterpret_cast<const u64*>(gib + 32 + jl);
    cn.u = *reinterpret_cast<const u64*>(gib + 64 + jl);
    asm volatile("" :: "v"(cr.u), "v"(cz.u), "v"(cn.u));

    f32x4 aR = (f32x4){0.f,0.f,0.f,0.f};
    f32x4 aZ = (f32x4){0.f,0.f,0.f,0.f};
    f32x4 aN = (f32x4){0.f,0.f,0.f,0.f};

    if (t > 0){
      // ---- poll the 32 wave-flags of (t-1, g): one 128B line, relaxed (no cache maintenance) ----
      const unsigned* fr = flags + ((size_t)(t-1)*4 + g)*32 + (l & 31);
      unsigned v;
      do { v = __hip_atomic_load(fr, __ATOMIC_RELAXED, __HIP_MEMORY_SCOPE_AGENT); } while (!__all((int)(v != 0u)));

      // ---- load B-fragments of h_{t-1}: row = batch bp, k = kt*32 + lh*8 (MALL-coherent u64 pairs) ----
      const u64* hsrc = reinterpret_cast<const u64*>(hh + ((size_t)(t-1)*BB + g*16 + bp)*HH + lh*8);
      union { u64 q[2]; f16x8 v8; } bF[16];
#pragma unroll
      for (int kt = 0; kt < 16; ++kt){
        bF[kt].q[0] = __hip_atomic_load(hsrc + kt*8,     __ATOMIC_RELAXED, __HIP_MEMORY_SCOPE_AGENT);
        bF[kt].q[1] = __hip_atomic_load(hsrc + kt*8 + 1, __ATOMIC_RELAXED, __HIP_MEMORY_SCOPE_AGENT);
      }
      // ---- gh = W_slice @ h : 48 MFMAs, 3 independent chains ----
#pragma unroll
      for (int kt = 0; kt < 16; ++kt){
        aR = __builtin_amdgcn_mfma_f32_16x16x32_f16(aW[0][kt], bF[kt].v8, aR, 0,0,0);
        aZ = __builtin_amdgcn_mfma_f32_16x16x32_f16(aW[1][kt], bF[kt].v8, aZ, 0,0,0);
        aN = __builtin_amdgcn_mfma_f32_16x16x32_f16(aW[2][kt], bF[kt].v8, aN, 0,0,0);
      }
    }

    // ---- gates (lane-local: 4 consecutive j, one batch) ----
#pragma unroll
    for (int r=0;r<4;r++){
      float rg = sigm((float)cr.h[r] + aR[r]);
      float zg = sigm((float)cz.h[r] + aZ[r]);
      float ng = tanh_f((float)cn.h[r] + rg*(aN[r] + bna[r]));
      hn.h[r] = (f16)((1.0f - zg)*ng + zg*(float)ho.h[r]);
    }
    ho.u = hn.u;

    // ---- publish: data store -> ack -> per-wave flag (all relaxed/sc0sc1, MALL-serialized) ----
    __hip_atomic_store(reinterpret_cast<u64*>(hh + ((size_t)t*BB + bglob)*HH + jglob), hn.u,
                       __ATOMIC_RELAXED, __HIP_MEMORY_SCOPE_AGENT);
    asm volatile("s_waitcnt vmcnt(0)" ::: "memory");
    __hip_atomic_store(flags + ((size_t)t*4 + g)*32 + (ksl*2 + wv), 1u,
                       __ATOMIC_RELAXED, __HIP_MEMORY_SCOPE_AGENT);
  }
}

// ---------------- rewards = sigmoid(h @ W_t + b_t) ----------------
__global__ void k_reward(const f16* __restrict__ hh, const float* __restrict__ wt,
                         const float* __restrict__ bt, float* __restrict__ out){
  int wv = threadIdx.x >> 6, l = threadIdx.x & 63;
  int idx = blockIdx.x*4 + wv;          // idx = b*1024 + t (output order [B][T])
  int b = idx >> 10, t = idx & 1023;
  const f16* hr = hh + ((size_t)t*64 + b)*HH;
  f16x8 hv = *reinterpret_cast<const f16x8*>(hr + l*8);
  float4 w0 = *reinterpret_cast<const float4*>(wt + l*8);
  float4 w1 = *reinterpret_cast<const float4*>(wt + l*8 + 4);
  float sum = (float)hv[0]*w0.x + (float)hv[1]*w0.y + (float)hv[2]*w0.z + (float)hv[3]*w0.w
            + (float)hv[4]*w1.x + (float)hv[5]*w1.y + (float)hv[6]*w1.z + (float)hv[7]*w1.w;
#pragma unroll
  for (int m=32;m>=1;m>>=1) sum += __shfl_xor(sum, m);
  if (l==0) out[idx] = sigm(sum + bt[0]);
}

extern "C" void kernel_launch(void* const* d_in, const int* in_sizes, int n_in,
                              void* d_out, int out_size, void* d_ws, size_t ws_size,
                              hipStream_t stream) {
  const float* s   = (const float*)d_in[0];
  const float* p   = (const float*)d_in[1];
  const float* wih = (const float*)d_in[2];
  const float* whh = (const float*)d_in[3];
  const float* bih = (const float*)d_in[4];
  const float* bhh = (const float*)d_in[5];
  const float* wt  = (const float*)d_in[6];
  const float* bt  = (const float*)d_in[7];
  float* out = (float*)d_out;

  char* ws = (char*)d_ws;
  size_t o = 0;
  auto take = [&](size_t bytes)->char*{ char* r = ws + o; o = (o + bytes + 255) & ~(size_t)255; return r; };
  f16*      x_h   = (f16*)   take((size_t)TT*BB*HH*2);       // 67 MB
  f16*      wih_h = (f16*)   take((size_t)G3*HH*2);
  f16*      whh_h = (f16*)   take((size_t)G3*HH*2);
  float*    biasf = (float*) take((size_t)G3*4);
  f16*      gi_s  = (f16*)   take((size_t)TT*BB*G3*2);       // 201 MB
  f16*      hh    = (f16*)   take((size_t)TT*BB*HH*2);       // 67 MB
  unsigned* flags = (unsigned*)take((size_t)TT*4*32*4);      // 512 KB
  (void)ws_size; (void)in_sizes; (void)n_in; (void)out_size;

  hipMemsetAsync(flags, 0, (size_t)TT*4*32*4, stream);
  k_prep  <<<3072, 256, 0, stream>>>(wih, whh, bih, bhh, wih_h, whh_h, biasf);
  k_buildx<<<TT*BB, 64, 0, stream>>>(s, p, x_h);
  k_gemm  <<<dim3(12, 512), 256, 0, stream>>>(x_h, wih_h, biasf, gi_s);
  k_scan  <<<128, 64, 0, stream>>>(whh_h, gi_s, bhh, hh, flags);
  k_reward<<<TT*BB/4, 256, 0, stream>>>(hh, wt, bt, out);
}

// Round 3
// 4538.466 us; speedup vs baseline: 1.6162x; 1.1186x over previous
//
#include <hip/hip_runtime.h>
#include <hip/hip_fp16.h>
#include <stdint.h>

#define TT 1024
#define BB 64
#define DHH 256
#define HH 512
#define G3 1536

typedef _Float16 f16;
typedef _Float16 f16x4 __attribute__((ext_vector_type(4)));
typedef _Float16 f16x8 __attribute__((ext_vector_type(8)));
typedef float f32x4 __attribute__((ext_vector_type(4)));
typedef unsigned long long u64;

__device__ __forceinline__ float sigm(float x){ return 1.0f/(1.0f+__expf(-x)); }
__device__ __forceinline__ float tanh_f(float x){ return 2.0f/(1.0f+__expf(-2.0f*x)) - 1.0f; }

// ---------------- prep: f32->f16 weights, folded bias ----------------
__global__ void k_prep(const float* __restrict__ wih, const float* __restrict__ whh,
                       const float* __restrict__ bih, const float* __restrict__ bhh,
                       f16* __restrict__ wih_h, f16* __restrict__ whh_h, float* __restrict__ biasf){
  int i = blockIdx.x*256 + threadIdx.x;
  if (i < G3*HH){ wih_h[i] = (f16)wih[i]; whh_h[i] = (f16)whh[i]; }
  // fold b_ih (all gates) + b_hh (r,z gates only; n-gate's b_hh stays inside r*(...))
  if (i < G3) biasf[i] = bih[i] + (i < 2*HH ? bhh[i] : 0.0f);
}

// ---------------- build x = concat(s, p.sum(axis=2)) as f16 [T*B][512] ----------------
__global__ void k_buildx(const float* __restrict__ s, const float* __restrict__ p, f16* __restrict__ x){
  int m = blockIdx.x;             // m = t*64 + b
  int t = m >> 6, b = m & 63;
  int l = threadIdx.x;            // 0..63 -> 4 floats each
  const float4* s4 = reinterpret_cast<const float4*>(s + ((size_t)b*TT + t)*DHH);
  const float4* p4 = reinterpret_cast<const float4*>(p + ((size_t)b*TT + t)*8*DHH);
  float4 sv = s4[l];
  float4 a  = p4[l];
#pragma unroll
  for (int k=1;k<8;k++){ float4 v = p4[k*64 + l]; a.x+=v.x; a.y+=v.y; a.z+=v.z; a.w+=v.w; }
  f16* xr = x + (size_t)m*HH;
  f16x4 hs = { (f16)sv.x,(f16)sv.y,(f16)sv.z,(f16)sv.w };
  f16x4 hp = { (f16)a.x,(f16)a.y,(f16)a.z,(f16)a.w };
  *reinterpret_cast<f16x4*>(xr + l*4)       = hs;
  *reinterpret_cast<f16x4*>(xr + 256 + l*4) = hp;
}

// ---------------- gi GEMM: D[wrow][xrow] = sum_k W_ih[wrow][k] * x[xrow][k]  (+bias) ----------------
// Writes gi in scan-friendly layout: gi[((t*16+ksl)*4+g)*16 + b'][96] f16, 96 = gate*32 + j'
#define LDAP 72
__global__ __launch_bounds__(256) void k_gemm(const f16* __restrict__ x, const f16* __restrict__ w,
                       const float* __restrict__ biasf, f16* __restrict__ gi){
  __shared__ f16 lA[128*LDAP];   // W tile   [128 wrows][64 k] padded
  __shared__ f16 lB[128*LDAP];   // x tile   [128 xrows][64 k] padded
  int by = blockIdx.x;           // wrow tile (12)
  int bx = blockIdx.y;           // xrow tile (512)
  int tid = threadIdx.x, l = tid & 63, wv = tid >> 6;
  int wm = wv >> 1, wn = wv & 1;

  f32x4 acc[4][4];
#pragma unroll
  for (int i=0;i<4;i++)
#pragma unroll
    for (int j=0;j<4;j++) acc[i][j] = (f32x4){0.f,0.f,0.f,0.f};

  for (int kt = 0; kt < 8; ++kt){
#pragma unroll
    for (int r = 0; r < 4; ++r){
      int c = tid + 256*r;            // 1024 chunks of 16B
      int row = c >> 3, o = c & 7;
      f16x8 va = *reinterpret_cast<const f16x8*>(w + (size_t)(by*128+row)*HH + kt*64 + o*8);
      f16x8 vb = *reinterpret_cast<const f16x8*>(x + (size_t)(bx*128+row)*HH + kt*64 + o*8);
      *reinterpret_cast<f16x8*>(&lA[row*LDAP + o*8]) = va;
      *reinterpret_cast<f16x8*>(&lB[row*LDAP + o*8]) = vb;
    }
    __syncthreads();
#pragma unroll
    for (int kk = 0; kk < 2; ++kk){
      f16x8 aF[4], bF[4];
#pragma unroll
      for (int mi=0;mi<4;mi++)
        aF[mi] = *reinterpret_cast<const f16x8*>(&lA[(wm*64+mi*16+(l&15))*LDAP + kk*32 + (l>>4)*8]);
#pragma unroll
      for (int ni=0;ni<4;ni++)
        bF[ni] = *reinterpret_cast<const f16x8*>(&lB[(wn*64+ni*16+(l&15))*LDAP + kk*32 + (l>>4)*8]);
#pragma unroll
      for (int mi=0;mi<4;mi++)
#pragma unroll
        for (int ni=0;ni<4;ni++)
          acc[mi][ni] = __builtin_amdgcn_mfma_f32_16x16x32_f16(aF[mi], bF[ni], acc[mi][ni], 0,0,0);
    }
    __syncthreads();
  }
  // epilogue: D m = (l>>4)*4+reg -> 4 consecutive wrows; n = l&15 -> xrow
#pragma unroll
  for (int mi=0;mi<4;mi++){
    int wrow0 = by*128 + wm*64 + mi*16 + (l>>4)*4;
    float4 bv = *reinterpret_cast<const float4*>(biasf + wrow0);
    int gate = wrow0 >> 9, j = wrow0 & 511, ksl = j >> 5, rp = gate*32 + (j&31);
#pragma unroll
    for (int ni=0;ni<4;ni++){
      int xrow = bx*128 + wn*64 + ni*16 + (l&15);
      int t = xrow >> 6, g = (xrow>>4)&3, bp = xrow & 15;
      size_t dst = ((((size_t)t*16 + ksl)*4 + g)*16 + bp)*96 + rp;
      union { u64 u; f16x4 h; } cv;
      cv.h = (f16x4){ (f16)(acc[mi][ni][0]+bv.x), (f16)(acc[mi][ni][1]+bv.y),
                      (f16)(acc[mi][ni][2]+bv.z), (f16)(acc[mi][ni][3]+bv.w) };
      *reinterpret_cast<u64*>(gi + dst) = cv.u;
    }
  }
}

// ---------------- persistent GRU scan: poll-the-data protocol ----------------
// 128 single-wave WGs = 4 batch-groups (16 batches) x 16 j-slices x 2 wave-halves.
// W_hh slice in 192 VGPRs. hh pre-poisoned to 0xFF; producer = ONE relaxed agent
// atomic u64 store per lane per step; consumer polls the data itself (poison check).
// gi is software-pipelined one step ahead (issue after poll, consume next step).
__global__ __launch_bounds__(64) void k_scan(const f16* __restrict__ whh_h, const f16* __restrict__ gi,
                      const float* __restrict__ bhh, f16* __restrict__ hh){
  const int bid = blockIdx.x;                       // 0..127
  const int g = bid & 3, ksl = (bid >> 2) & 15, wv = bid >> 6;
  const int l = threadIdx.x;                        // 0..63
  const int lm = l & 15, lh = l >> 4;

  // persistent A-fragments: aW[gate][kt], W row = gate*512 + ksl*32 + wv*16 + lm, k = kt*32 + lh*8
  f16x8 aW[3][16];
#pragma unroll
  for (int gate = 0; gate < 3; ++gate){
    const f16* wr = whh_h + ((size_t)gate*512 + ksl*32 + wv*16 + lm)*HH + lh*8;
#pragma unroll
    for (int kt = 0; kt < 16; ++kt)
      aW[gate][kt] = *reinterpret_cast<const f16x8*>(wr + kt*32);
  }
  const int jl    = wv*16 + lh*4;                   // first of 4 j-locals this lane owns
  const int jglob = ksl*32 + jl;
  float4 bnv = *reinterpret_cast<const float4*>(bhh + 2*HH + jglob);   // b_hh n-gate
  float bna[4] = {bnv.x, bnv.y, bnv.z, bnv.w};
  const int bp = lm, bglob = g*16 + bp;

  union U64H { u64 u; f16x4 h; };
  U64H cA[3], cB[3], ho, hn;
  ho.u = 0ull;

  // ---- t = 0 peel: h_{-1} = 0, no poll; prefetch gi(1) into cB ----
  {
    const f16* g0 = gi + ((((size_t)0*16 + ksl)*4 + g)*16 + bp)*96;
    cA[0].u = *reinterpret_cast<const u64*>(g0 + jl);
    cA[1].u = *reinterpret_cast<const u64*>(g0 + 32 + jl);
    cA[2].u = *reinterpret_cast<const u64*>(g0 + 64 + jl);
    const f16* g1 = gi + ((((size_t)1*16 + ksl)*4 + g)*16 + bp)*96;
    cB[0].u = *reinterpret_cast<const u64*>(g1 + jl);
    cB[1].u = *reinterpret_cast<const u64*>(g1 + 32 + jl);
    cB[2].u = *reinterpret_cast<const u64*>(g1 + 64 + jl);
#pragma unroll
    for (int r = 0; r < 4; ++r){
      float rg = sigm((float)cA[0].h[r]);
      float zg = sigm((float)cA[1].h[r]);
      float ng = tanh_f((float)cA[2].h[r] + rg*bna[r]);
      hn.h[r] = (f16)((1.0f - zg)*ng);
    }
    ho.u = hn.u;
    __hip_atomic_store(reinterpret_cast<u64*>(hh + ((size_t)0*BB + bglob)*HH + jglob), hn.u,
                       __ATOMIC_RELAXED, __HIP_MEMORY_SCOPE_AGENT);
  }

#define BODY(T, CUR, NXT, DO_NXT)                                                                    \
  {                                                                                                  \
    const int t_ = (T);                                                                              \
    union BC { u64 q[2]; f16x8 v8; } bF[16];                                                         \
    const u64* hsrc = reinterpret_cast<const u64*>(                                                  \
        hh + ((size_t)(t_-1)*BB + g*16 + bp)*HH + lh*8);                                             \
    int ok;                                                                                          \
    do {                                                                                             \
      ok = 1;                                                                                        \
      _Pragma("unroll")                                                                              \
      for (int kt = 0; kt < 16; ++kt){                                                               \
        bF[kt].q[0] = __hip_atomic_load(hsrc + kt*8,   __ATOMIC_RELAXED, __HIP_MEMORY_SCOPE_AGENT);  \
        bF[kt].q[1] = __hip_atomic_load(hsrc + kt*8+1, __ATOMIC_RELAXED, __HIP_MEMORY_SCOPE_AGENT);  \
        ok &= ((unsigned)bF[kt].q[0] != 0xFFFFFFFFu);                                                \
        ok &= ((unsigned)bF[kt].q[1] != 0xFFFFFFFFu);                                                \
      }                                                                                              \
    } while (!__all(ok));                                                                            \
    if (DO_NXT){                                                                                     \
      const int tn_ = (t_+1 < TT) ? t_+1 : t_;                                                       \
      const f16* gn = gi + ((((size_t)tn_*16 + ksl)*4 + g)*16 + bp)*96;                              \
      NXT[0].u = *reinterpret_cast<const u64*>(gn + jl);                                             \
      NXT[1].u = *reinterpret_cast<const u64*>(gn + 32 + jl);                                        \
      NXT[2].u = *reinterpret_cast<const u64*>(gn + 64 + jl);                                        \
    }                                                                                                \
    f32x4 aR = (f32x4){0.f,0.f,0.f,0.f};                                                             \
    f32x4 aZ = (f32x4){0.f,0.f,0.f,0.f};                                                             \
    f32x4 aN = (f32x4){0.f,0.f,0.f,0.f};                                                             \
    _Pragma("unroll")                                                                                \
    for (int kt = 0; kt < 16; ++kt){                                                                 \
      aR = __builtin_amdgcn_mfma_f32_16x16x32_f16(aW[0][kt], bF[kt].v8, aR, 0,0,0);                  \
      aZ = __builtin_amdgcn_mfma_f32_16x16x32_f16(aW[1][kt], bF[kt].v8, aZ, 0,0,0);                  \
      aN = __builtin_amdgcn_mfma_f32_16x16x32_f16(aW[2][kt], bF[kt].v8, aN, 0,0,0);                  \
    }                                                                                                \
    _Pragma("unroll")                                                                                \
    for (int r = 0; r < 4; ++r){                                                                     \
      float rg = sigm((float)CUR[0].h[r] + aR[r]);                                                   \
      float zg = sigm((float)CUR[1].h[r] + aZ[r]);                                                   \
      float ng = tanh_f((float)CUR[2].h[r] + rg*(aN[r] + bna[r]));                                   \
      hn.h[r] = (f16)((1.0f - zg)*ng + zg*(float)ho.h[r]);                                           \
    }                                                                                                \
    ho.u = hn.u;                                                                                     \
    __hip_atomic_store(reinterpret_cast<u64*>(hh + ((size_t)t_*BB + bglob)*HH + jglob), hn.u,        \
                       __ATOMIC_RELAXED, __HIP_MEMORY_SCOPE_AGENT);                                  \
  }

  for (int t = 1; t < TT-1; t += 2){
    BODY(t,   cB, cA, 1)
    BODY(t+1, cA, cB, 1)
  }
  BODY(TT-1, cB, cA, 0)
#undef BODY
}

// ---------------- rewards = sigmoid(h @ W_t + b_t) ----------------
__global__ void k_reward(const f16* __restrict__ hh, const float* __restrict__ wt,
                         const float* __restrict__ bt, float* __restrict__ out){
  int wv = threadIdx.x >> 6, l = threadIdx.x & 63;
  int idx = blockIdx.x*4 + wv;          // idx = b*1024 + t (output order [B][T])
  int b = idx >> 10, t = idx & 1023;
  const f16* hr = hh + ((size_t)t*64 + b)*HH;
  f16x8 hv = *reinterpret_cast<const f16x8*>(hr + l*8);
  float4 w0 = *reinterpret_cast<const float4*>(wt + l*8);
  float4 w1 = *reinterpret_cast<const float4*>(wt + l*8 + 4);
  float sum = (float)hv[0]*w0.x + (float)hv[1]*w0.y + (float)hv[2]*w0.z + (float)hv[3]*w0.w
            + (float)hv[4]*w1.x + (float)hv[5]*w1.y + (float)hv[6]*w1.z + (float)hv[7]*w1.w;
#pragma unroll
  for (int m=32;m>=1;m>>=1) sum += __shfl_xor(sum, m);
  if (l==0) out[idx] = sigm(sum + bt[0]);
}

extern "C" void kernel_launch(void* const* d_in, const int* in_sizes, int n_in,
                              void* d_out, int out_size, void* d_ws, size_t ws_size,
                              hipStream_t stream) {
  const float* s   = (const float*)d_in[0];
  const float* p   = (const float*)d_in[1];
  const float* wih = (const float*)d_in[2];
  const float* whh = (const float*)d_in[3];
  const float* bih = (const float*)d_in[4];
  const float* bhh = (const float*)d_in[5];
  const float* wt  = (const float*)d_in[6];
  const float* bt  = (const float*)d_in[7];
  float* out = (float*)d_out;

  char* ws = (char*)d_ws;
  size_t o = 0;
  auto take = [&](size_t bytes)->char*{ char* r = ws + o; o = (o + bytes + 255) & ~(size_t)255; return r; };
  f16*      x_h   = (f16*)   take((size_t)TT*BB*HH*2);       // 67 MB
  f16*      wih_h = (f16*)   take((size_t)G3*HH*2);
  f16*      whh_h = (f16*)   take((size_t)G3*HH*2);
  float*    biasf = (float*) take((size_t)G3*4);
  f16*      gi_s  = (f16*)   take((size_t)TT*BB*G3*2);       // 201 MB
  f16*      hh    = (f16*)   take((size_t)TT*BB*HH*2);       // 67 MB
  (void)ws_size; (void)in_sizes; (void)n_in; (void)out_size;

  hipMemsetAsync(hh, 0xFF, (size_t)TT*BB*HH*2, stream);      // poison: poll-the-data sentinel
  k_prep  <<<3072, 256, 0, stream>>>(wih, whh, bih, bhh, wih_h, whh_h, biasf);
  k_buildx<<<TT*BB, 64, 0, stream>>>(s, p, x_h);
  k_gemm  <<<dim3(12, 512), 256, 0, stream>>>(x_h, wih_h, biasf, gi_s);
  k_scan  <<<128, 64, 0, stream>>>(whh_h, gi_s, bhh, hh);
  k_reward<<<TT*BB/4, 256, 0, stream>>>(hh, wt, bt, out);
}